// Round 1
// baseline (80.801 us; speedup 1.0000x reference)
//
#include <hip/hip_runtime.h>

namespace {
constexpr int kV    = 21;
constexpr int kK    = 3;
constexpr int kCin  = 3;
constexpr int kN    = 64;
constexpr int kT    = 256;
constexpr int kNR   = 256;          // r values per n
constexpr int kNCh  = 1344;         // V*C_OUT
constexpr int kInner = kNCh * 256;  // 344064 elements per n
constexpr float kEps = 1e-5f;

// workspace layout (in floats)
constexpr int X4_OFF = 0;                         // [64][3][4][21]  = 16128
constexpr int U_OFF  = 16384;                     // [64][256][21][3] = 1032192
constexpr int ST_OFF = U_OFF + kN * kNR * kV * kK; // [1344][2]       = 2688
}

// ---------------------------------------------------------------------------
// k1: X4[n][ci][q][v] = sum_{t=q*64}^{q*64+63} x[n][ci][t][v]
// ---------------------------------------------------------------------------
__global__ __launch_bounds__(256) void k1_x4(const float* __restrict__ x,
                                             float* __restrict__ x4) {
  int tid = blockIdx.x * 256 + threadIdx.x;
  if (tid >= kN * kCin * 4 * kV) return;
  int v  = tid % kV;
  int q  = (tid / kV) & 3;
  int nc = tid / (4 * kV);                 // n*3 + ci
  const float* p = x + (nc * kT + q * 64) * kV + v;
  float s = 0.f;
#pragma unroll
  for (int t = 0; t < 64; ++t) s += p[t * kV];
  x4[tid] = s;
}

// ---------------------------------------------------------------------------
// k2: U[n][r][w][k] = sum_v A[k][v][w] * S[k][v]
//     S[k][v] = sum_ci W[o][ci]*X4[n][ci][q][v] + 64*b[o],  g=r*3+k, o=g>>2, q=g&3
// one 64-thread block per (n,r)
// ---------------------------------------------------------------------------
__global__ __launch_bounds__(64) void k2_u(const float* __restrict__ x4,
                                           const float* __restrict__ A,
                                           const float* __restrict__ W,
                                           const float* __restrict__ bias,
                                           float* __restrict__ U) {
  int nb = blockIdx.x;                     // n*256 + r
  int n = nb >> 8, r = nb & 255;
  __shared__ float S[kK][kV];
  int i = threadIdx.x;
  if (i < kK * kV) {
    int k = i / kV, v = i - k * kV;
    int g = r * 3 + k;
    int o = g >> 2, q = g & 3;
    const float* xp = x4 + (n * kCin * 4 + q) * kV + v;
    S[k][v] = W[o * 3 + 0] * xp[0] + W[o * 3 + 1] * xp[4 * kV] +
              W[o * 3 + 2] * xp[8 * kV] + 64.f * bias[o];
  }
  __syncthreads();
  if (i < kK * kV) {
    int w = i / 3, k = i - w * 3;
    const float* a = A + k * kV * kV + w;  // A[k][v][w], stride kV over v
    float z = 0.f;
#pragma unroll
    for (int v = 0; v < kV; ++v) z += a[v * kV] * S[k][v];
    U[(nb * kV + w) * 3 + k] = z;
  }
}

// ---------------------------------------------------------------------------
// e(n, inner) with inner = r*1344 + w*64 + co:
//   e = sum_k W_emb[co][k]*U[n][r][w][k] + b_emb[co] + pos[w][co]
// k3: per-channel (ch = inner>>8) batch stats over (n, 256 inners)
// ---------------------------------------------------------------------------
__global__ __launch_bounds__(256) void k3_stats(
    const float* __restrict__ U, const float* __restrict__ W_emb,
    const float* __restrict__ b_emb, const float* __restrict__ pos,
    const float* __restrict__ gamma, const float* __restrict__ beta,
    float* __restrict__ stats) {
  int ch = blockIdx.x;
  int tid = threadIdx.x;
  int inner = ch * 256 + tid;
  int r = inner / kNCh;
  int rem = inner - r * kNCh;
  int w = rem >> 6;
  int co = rem & 63;
  float we0 = W_emb[co * 3 + 0], we1 = W_emb[co * 3 + 1], we2 = W_emb[co * 3 + 2];
  float cadd = b_emb[co] + pos[w * 64 + co];
  const float* u = U + (r * kV + w) * 3;
  float s = 0.f, sq = 0.f;
  for (int n = 0; n < kN; ++n) {
    const float* up = u + n * (kNR * kV * 3);
    float e = we0 * up[0] + we1 * up[1] + we2 * up[2] + cadd;
    s += e;
    sq += e * e;
  }
  // 64-lane shuffle reduce, then cross-wave via LDS
  for (int off = 32; off > 0; off >>= 1) {
    s += __shfl_down(s, off);
    sq += __shfl_down(sq, off);
  }
  __shared__ float ls[4], lq[4];
  int wv = tid >> 6;
  if ((tid & 63) == 0) { ls[wv] = s; lq[wv] = sq; }
  __syncthreads();
  if (tid == 0) {
    float S1 = ls[0] + ls[1] + ls[2] + ls[3];
    float S2 = lq[0] + lq[1] + lq[2] + lq[3];
    float mean = S1 * (1.f / 16384.f);
    float var = S2 * (1.f / 16384.f) - mean * mean;
    float inv = rsqrtf(var + kEps);
    float sc = gamma[ch] * inv;
    stats[ch * 2 + 0] = sc;
    stats[ch * 2 + 1] = beta[ch] - mean * sc;
  }
}

// ---------------------------------------------------------------------------
// k4: out flat index == BN-input flat index. One block per (n, ch).
// ---------------------------------------------------------------------------
__global__ __launch_bounds__(256) void k4_out(
    const float* __restrict__ U, const float* __restrict__ W_emb,
    const float* __restrict__ b_emb, const float* __restrict__ pos,
    const float* __restrict__ stats, float* __restrict__ out) {
  int b = blockIdx.x;            // n*1344 + ch
  int n = b / kNCh;
  int ch = b - n * kNCh;
  int tid = threadIdx.x;
  int inner = ch * 256 + tid;
  int r = inner / kNCh;
  int rem = inner - r * kNCh;
  int w = rem >> 6;
  int co = rem & 63;
  const float* up = U + ((n * kNR + r) * kV + w) * 3;
  float e = W_emb[co * 3 + 0] * up[0] + W_emb[co * 3 + 1] * up[1] +
            W_emb[co * 3 + 2] * up[2] + b_emb[co] + pos[w * 64 + co];
  out[n * kInner + inner] = e * stats[ch * 2 + 0] + stats[ch * 2 + 1];
}

extern "C" void kernel_launch(void* const* d_in, const int* in_sizes, int n_in,
                              void* d_out, int out_size, void* d_ws, size_t ws_size,
                              hipStream_t stream) {
  const float* x      = (const float*)d_in[0];
  const float* A      = (const float*)d_in[1];
  const float* conv_w = (const float*)d_in[2];
  const float* conv_b = (const float*)d_in[3];
  const float* W_emb  = (const float*)d_in[4];
  const float* b_emb  = (const float*)d_in[5];
  const float* pos    = (const float*)d_in[6];
  const float* gamma  = (const float*)d_in[7];
  const float* beta   = (const float*)d_in[8];
  float* out = (float*)d_out;
  float* ws  = (float*)d_ws;

  float* x4    = ws + X4_OFF;
  float* U     = ws + U_OFF;
  float* stats = ws + ST_OFF;

  k1_x4<<<63, 256, 0, stream>>>(x, x4);
  k2_u<<<kN * kNR, 64, 0, stream>>>(x4, A, conv_w, conv_b, U);
  k3_stats<<<kNCh, 256, 0, stream>>>(U, W_emb, b_emb, pos, gamma, beta, stats);
  k4_out<<<kN * kNCh, 256, 0, stream>>>(U, W_emb, b_emb, pos, stats, out);
}

// Round 3
// 63.796 us; speedup vs baseline: 1.2666x; 1.2666x over previous
//
#include <hip/hip_runtime.h>

namespace {
constexpr int kV    = 21;
constexpr int kCin  = 3;
constexpr int kT    = 256;
constexpr int kNCh  = 1344;         // V*C_OUT
constexpr int kInner = kNCh * 256;  // 344064 elements per n
constexpr float kEps = 1e-5f;

typedef float f32x4 __attribute__((ext_vector_type(4)));

// workspace layout (in floats; M is double-typed, float-offset kept 8B-aligned)
constexpr int X4_OFF = 0;                          // [64][3][4][21] = 16128
constexpr int U_OFF  = 16384;                      // [64][256][21][3] = 1032192
constexpr int M_OFF  = U_OFF + 64 * 256 * 21 * 3;  // doubles: [5376][9] = 48384 dbl
constexpr int ST_OFF = M_OFF + 5376 * 9 * 2;       // [1344][2] floats
}

// ---------------------------------------------------------------------------
// k1: X4[n][ci][q][v] = sum_{t=q*64}^{q*64+63} x[n][ci][t][v]
// 252 blocks x 64 threads (one thread per output)
// ---------------------------------------------------------------------------
__global__ __launch_bounds__(64) void k1_x4(const float* __restrict__ x,
                                            float* __restrict__ x4) {
  int tid = blockIdx.x * 64 + threadIdx.x;   // < 16128 exactly
  int v  = tid % kV;
  int q  = (tid / kV) & 3;
  int nc = tid / (4 * kV);                   // n*3 + ci
  const float* p = x + (nc * kT + q * 64) * kV + v;
  float s = 0.f;
#pragma unroll
  for (int t = 0; t < 64; ++t) s += p[t * kV];
  x4[tid] = s;
}

// ---------------------------------------------------------------------------
// k2: U[n][r][w][k] = sum_v A[k][v][w] * S[k][v]
//     S[k][v] = sum_ci W[o][ci]*X4[n][ci][q][v] + 64*b[o], g=r*3+k, o=g>>2, q=g&3
// one 64-thread block per (n,r)
// ---------------------------------------------------------------------------
__global__ __launch_bounds__(64) void k2_u(const float* __restrict__ x4,
                                           const float* __restrict__ A,
                                           const float* __restrict__ W,
                                           const float* __restrict__ bias,
                                           float* __restrict__ U) {
  int nb = blockIdx.x;                     // n*256 + r
  int n = nb >> 8, r = nb & 255;
  __shared__ float S[3][kV];
  int i = threadIdx.x;
  if (i < 3 * kV) {
    int k = i / kV, v = i - k * kV;
    int g = r * 3 + k;
    int o = g >> 2, q = g & 3;
    const float* xp = x4 + (n * kCin * 4 + q) * kV + v;
    S[k][v] = W[o * 3 + 0] * xp[0] + W[o * 3 + 1] * xp[4 * kV] +
              W[o * 3 + 2] * xp[8 * kV] + 64.f * bias[o];
  }
  __syncthreads();
  if (i < 3 * kV) {
    int w = i / 3, k = i - w * 3;
    const float* a = A + k * kV * kV + w;   // A[k][v][w], stride kV over v
    float z = 0.f;
#pragma unroll
    for (int v = 0; v < kV; ++v) z += a[v * kV] * S[k][v];
    U[(nb * kV + w) * 3 + k] = z;
  }
}

// ---------------------------------------------------------------------------
// k3a: per-(r,w) moments over n (double precision):
//   M[p][0..8] = sum_n (u0^2, u0u1, u0u2, u1^2, u1u2, u2^2, u0, u1, u2)
// one wave per p = r*21+w; lane = n
// ---------------------------------------------------------------------------
__global__ __launch_bounds__(256) void k3a_mom(const float* __restrict__ U,
                                               double* __restrict__ M) {
  int p = blockIdx.x * 4 + (threadIdx.x >> 6);   // < 5376
  int lane = threadIdx.x & 63;                   // n
  int r = p / kV, w = p - r * kV;
  const float* up = U + ((lane * 256 + r) * kV + w) * 3;
  double u0 = up[0], u1 = up[1], u2 = up[2];
  double m[9] = {u0 * u0, u0 * u1, u0 * u2, u1 * u1, u1 * u2, u2 * u2, u0, u1, u2};
#pragma unroll
  for (int off = 1; off < 64; off <<= 1) {
#pragma unroll
    for (int i = 0; i < 9; ++i) m[i] += __shfl_xor(m[i], off);
  }
  if (lane == 0) {
#pragma unroll
    for (int i = 0; i < 9; ++i) M[p * 9 + i] = m[i];
  }
}

// ---------------------------------------------------------------------------
// k3b: per-channel BN stats from moments. One wave per channel, lane = co.
//   e(n,inner) = we[co]·u(n,r,w) + c(w,co);  Σ_n e, Σ_n e² from M.
// ---------------------------------------------------------------------------
__global__ __launch_bounds__(256) void k3b_stats(
    const double* __restrict__ M, const float* __restrict__ W_emb,
    const float* __restrict__ b_emb, const float* __restrict__ pos,
    const float* __restrict__ gamma, const float* __restrict__ beta,
    float* __restrict__ stats) {
  int ch = blockIdx.x * 4 + (threadIdx.x >> 6);   // < 1344
  int co = threadIdx.x & 63;
  double we0 = W_emb[co * 3 + 0], we1 = W_emb[co * 3 + 1], we2 = W_emb[co * 3 + 2];
  double be = b_emb[co];
  double S1 = 0.0, S2 = 0.0;
#pragma unroll
  for (int j = 0; j < 4; ++j) {
    int inner = ch * 256 + j * 64 + co;
    int r = inner / kNCh;
    int rem = inner - r * kNCh;
    int w = rem >> 6;                              // constant across the wave
    const double* m = M + (r * kV + w) * 9;
    double c = be + (double)pos[w * 64 + co];
    double lin = we0 * m[6] + we1 * m[7] + we2 * m[8];
    S1 += lin + 64.0 * c;
    S2 += we0 * we0 * m[0] + 2.0 * we0 * we1 * m[1] + 2.0 * we0 * we2 * m[2] +
          we1 * we1 * m[3] + 2.0 * we1 * we2 * m[4] + we2 * we2 * m[5] +
          2.0 * c * lin + 64.0 * c * c;
  }
#pragma unroll
  for (int off = 1; off < 64; off <<= 1) {
    S1 += __shfl_xor(S1, off);
    S2 += __shfl_xor(S2, off);
  }
  if (co == 0) {
    double mean = S1 * (1.0 / 16384.0);
    double var = S2 * (1.0 / 16384.0) - mean * mean;
    double inv = rsqrt(var + (double)kEps);
    float sc = (float)((double)gamma[ch] * inv);
    stats[ch * 2 + 0] = sc;
    stats[ch * 2 + 1] = (float)((double)beta[ch] - mean * (double)gamma[ch] * inv);
  }
}

// ---------------------------------------------------------------------------
// k4: elementwise epilogue; out flat index == BN-input flat index.
// 4 floats/thread, float4 nontemporal stores. 21504 blocks x 256.
// ---------------------------------------------------------------------------
__global__ __launch_bounds__(256) void k4_out(
    const float* __restrict__ U, const float* __restrict__ W_emb,
    const float* __restrict__ b_emb, const float* __restrict__ pos,
    const float* __restrict__ stats, float* __restrict__ out) {
  int b = blockIdx.x;
  int n = b / 336;
  int bi = b - n * 336;
  int inner0 = bi * 1024 + threadIdx.x * 4;   // 4-aligned; group shares (r,w,ch)
  int r = inner0 / kNCh;
  int rem = inner0 - r * kNCh;
  int w = rem >> 6;
  int co = rem & 63;                          // 4-aligned
  int ch = inner0 >> 8;
  const float* up = U + ((n * 256 + r) * kV + w) * 3;
  float u0 = up[0], u1 = up[1], u2 = up[2];
  float sc = stats[ch * 2 + 0], sh = stats[ch * 2 + 1];
  const float* we = W_emb + co * 3;
  const float* pe = pos + w * 64 + co;
  const float* bb = b_emb + co;
  f32x4 o;
  o.x = (we[0] * u0 + we[1] * u1 + we[2] * u2 + bb[0] + pe[0]) * sc + sh;
  o.y = (we[3] * u0 + we[4] * u1 + we[5] * u2 + bb[1] + pe[1]) * sc + sh;
  o.z = (we[6] * u0 + we[7] * u1 + we[8] * u2 + bb[2] + pe[2]) * sc + sh;
  o.w = (we[9] * u0 + we[10] * u1 + we[11] * u2 + bb[3] + pe[3]) * sc + sh;
  __builtin_nontemporal_store(o, (f32x4*)(out + (size_t)n * kInner + inner0));
}

extern "C" void kernel_launch(void* const* d_in, const int* in_sizes, int n_in,
                              void* d_out, int out_size, void* d_ws, size_t ws_size,
                              hipStream_t stream) {
  const float* x      = (const float*)d_in[0];
  const float* A      = (const float*)d_in[1];
  const float* conv_w = (const float*)d_in[2];
  const float* conv_b = (const float*)d_in[3];
  const float* W_emb  = (const float*)d_in[4];
  const float* b_emb  = (const float*)d_in[5];
  const float* pos    = (const float*)d_in[6];
  const float* gamma  = (const float*)d_in[7];
  const float* beta   = (const float*)d_in[8];
  float* out = (float*)d_out;
  float* ws  = (float*)d_ws;

  float*  x4    = ws + X4_OFF;
  float*  U     = ws + U_OFF;
  double* M     = (double*)(ws + M_OFF);
  float*  stats = ws + ST_OFF;

  k1_x4<<<252, 64, 0, stream>>>(x, x4);
  k2_u<<<64 * 256, 64, 0, stream>>>(x4, A, conv_w, conv_b, U);
  k3a_mom<<<1344, 256, 0, stream>>>(U, M);
  k3b_stats<<<336, 256, 0, stream>>>(M, W_emb, b_emb, pos, gamma, beta, stats);
  k4_out<<<64 * 336, 256, 0, stream>>>(U, W_emb, b_emb, pos, stats, out);
}